// Round 5
// baseline (783.420 us; speedup 1.0000x reference)
//
#include <hip/hip_runtime.h>

#define N_ 8
#define C_ 256
#define HW_ 4096

typedef __bf16 bf16x8 __attribute__((ext_vector_type(8)));
typedef float f32x4 __attribute__((ext_vector_type(4)));
typedef float f32x16 __attribute__((ext_vector_type(16)));
typedef unsigned short u16x8 __attribute__((ext_vector_type(8)));
typedef unsigned int uint2v __attribute__((ext_vector_type(2)));

#define MFMA(a, b, c)   __builtin_amdgcn_mfma_f32_16x16x32_bf16(a, b, c, 0, 0, 0)
#define MFMA32(a, b, c) __builtin_amdgcn_mfma_f32_32x32x16_bf16(a, b, c, 0, 0, 0)

static __device__ __forceinline__ unsigned short f2bf(float f) {
    union { float f; unsigned int u; } v; v.f = f;
    unsigned int u = v.u;
    return (unsigned short)((u + 0x7FFFu + ((u >> 16) & 1u)) >> 16);  // RNE
}

static __device__ __forceinline__ bf16x8 pack_bf8(float4 a, float4 b) {
    u16x8 t;
    t[0] = f2bf(a.x); t[1] = f2bf(a.y); t[2] = f2bf(a.z); t[3] = f2bf(a.w);
    t[4] = f2bf(b.x); t[5] = f2bf(b.y); t[6] = f2bf(b.z); t[7] = f2bf(b.w);
    return __builtin_bit_cast(bf16x8, t);
}

static __device__ __forceinline__ unsigned cvt_pk_bf16(float lo, float hi) {
    unsigned r;
    asm("v_cvt_pk_bf16_f32 %0, %1, %2" : "=v"(r) : "v"(lo), "v"(hi));
    return r;
}

static __device__ __forceinline__ void plswap(unsigned& a, unsigned& b) {
#if __has_builtin(__builtin_amdgcn_permlane32_swap)
    uint2v r = __builtin_amdgcn_permlane32_swap(a, b, false, false);
    a = r[0]; b = r[1];
#else
    asm volatile("v_permlane32_swap_b32 %0, %1" : "+v"(a), "+v"(b));
#endif
}

// ---------------------------------------------------------------------------
// Kernel 1: theta/phi/g 1x1 convs.  x:[N,C,HW] f32 -> thetaT/phiT:[N,HW,C] bf16
// (theta pre-scaled by C^-0.5), gC:[N,C,HW] bf16 WITHOUT b_g (BN absorbs it).
// theta/phi outputs are routed through a padded LDS transpose tile so global
// writes are 128B-contiguous row segments (was 8B scatter -> write amplif.).
// ---------------------------------------------------------------------------
__global__ __launch_bounds__(256) void qkv_kernel(
    const float* __restrict__ x,
    const float* __restrict__ w_theta, const float* __restrict__ b_theta,
    const float* __restrict__ w_phi,   const float* __restrict__ b_phi,
    const float* __restrict__ w_g,     const float* __restrict__ b_g,
    unsigned short* __restrict__ thetaT, unsigned short* __restrict__ phiT,
    unsigned short* __restrict__ gC)
{
    __shared__ unsigned short xT[64 * 264];     // 33 KB
    __shared__ unsigned short tile[64 * 72];    // 9 KB transpose tile [hw][o]
    const int tid = threadIdx.x;
    const int hw0 = blockIdx.x * 64;
    const int n   = blockIdx.y;
    const float* xb = x + (size_t)n * C_ * HW_;
    for (int i = 0; i < 16; ++i) {
        int e   = tid + i * 256;
        int c   = e >> 4;
        int hw4 = (e & 15) << 2;
        float4 v = *reinterpret_cast<const float4*>(xb + (size_t)c * HW_ + hw0 + hw4);
        xT[(hw4 + 0) * 264 + c] = f2bf(v.x);
        xT[(hw4 + 1) * 264 + c] = f2bf(v.y);
        xT[(hw4 + 2) * 264 + c] = f2bf(v.z);
        xT[(hw4 + 3) * 264 + c] = f2bf(v.w);
    }
    __syncthreads();

    const int w = tid >> 6, lane = tid & 63;
    const int g16 = lane >> 4, l16 = lane & 15;

    const float* Wp[3] = { w_theta, w_phi, w_g };
    const float* Bp[3] = { b_theta, b_phi, b_g };

    for (int ot = 0; ot < 4; ++ot) {
        const int oB    = ot * 64;
        const int wrow  = oB + w * 16 + l16;
        const int orow0 = oB + w * 16 + g16 * 4;
        #pragma unroll
        for (int wt = 0; wt < 3; ++wt) {
            const float* W = Wp[wt];
            bf16x8 aw[8];
            #pragma unroll
            for (int kk = 0; kk < 8; ++kk) {
                const float* wp = W + (size_t)wrow * C_ + kk * 32 + g16 * 8;
                float4 f0 = *reinterpret_cast<const float4*>(wp);
                float4 f1 = *reinterpret_cast<const float4*>(wp + 4);
                aw[kk] = pack_bf8(f0, f1);
            }
            f32x4 acc[4];
            #pragma unroll
            for (int cb = 0; cb < 4; ++cb) {
                acc[cb][0] = 0.f; acc[cb][1] = 0.f; acc[cb][2] = 0.f; acc[cb][3] = 0.f;
            }
            #pragma unroll
            for (int kk = 0; kk < 8; ++kk) {
                #pragma unroll
                for (int cb = 0; cb < 4; ++cb) {
                    bf16x8 b = *reinterpret_cast<const bf16x8*>(
                        &xT[(cb * 16 + l16) * 264 + kk * 32 + g16 * 8]);
                    acc[cb] = MFMA(aw[kk], b, acc[cb]);
                }
            }
            const float* bp = Bp[wt];
            float bj0 = bp[orow0], bj1 = bp[orow0 + 1], bj2 = bp[orow0 + 2], bj3 = bp[orow0 + 3];
            if (wt == 2) { bj0 = 0.f; bj1 = 0.f; bj2 = 0.f; bj3 = 0.f; }
            if (wt < 2) {
                const float sc = (wt == 0) ? 0.0625f : 1.0f;
                __syncthreads();   // previous tile readers done
                #pragma unroll
                for (int cb = 0; cb < 4; ++cb) {
                    ushort4 pk;
                    pk.x = f2bf((acc[cb][0] + bj0) * sc);
                    pk.y = f2bf((acc[cb][1] + bj1) * sc);
                    pk.z = f2bf((acc[cb][2] + bj2) * sc);
                    pk.w = f2bf((acc[cb][3] + bj3) * sc);
                    // tile[hw][o'] ; o' = w*16 + g16*4 + j
                    *reinterpret_cast<ushort4*>(&tile[(cb * 16 + l16) * 72 + w * 16 + g16 * 4]) = pk;
                }
                __syncthreads();
                unsigned short* dst = (wt == 0) ? thetaT : phiT;
                #pragma unroll
                for (int i = 0; i < 2; ++i) {
                    int e = tid + i * 256;
                    int row = e >> 3, seg = (e & 7) << 3;
                    *reinterpret_cast<uint4*>(
                        &dst[((size_t)n * HW_ + hw0 + row) * C_ + oB + seg]) =
                        *reinterpret_cast<const uint4*>(&tile[row * 72 + seg]);
                }
            } else {
                #pragma unroll
                for (int cb = 0; cb < 4; ++cb) {
                    int hw = hw0 + cb * 16 + l16;
                    gC[((size_t)n * C_ + orow0 + 0) * HW_ + hw] = f2bf(acc[cb][0]);
                    gC[((size_t)n * C_ + orow0 + 1) * HW_ + hw] = f2bf(acc[cb][1]);
                    gC[((size_t)n * C_ + orow0 + 2) * HW_ + hw] = f2bf(acc[cb][2]);
                    gC[((size_t)n * C_ + orow0 + 3) * HW_ + hw] = f2bf(acc[cb][3]);
                }
            }
        }
    }
}

// ---------------------------------------------------------------------------
// Kernel 2: flash attention, 32x32 MFMA, swapped QK^T, in-register softmax,
// P via cvt_pk + permlane32_swap, defer-max.  NO LDS staging: every MFMA
// fragment is a contiguous 16B slice of phiT ([HW,C]) / gC ([C,HW]) read
// straight through L2 (K/V per batch = 4MB = one XCD L2; n = bid&7).
// Barriers only in the final 2-way kv-half merge.
// ---------------------------------------------------------------------------
__global__ __launch_bounds__(256, 2) void attn_kernel(
    const unsigned short* __restrict__ thetaT,
    const unsigned short* __restrict__ phiT,
    const unsigned short* __restrict__ gC,
    unsigned short* __restrict__ tpgT)
{
    __shared__ float Obuf[2][32 * 256];   // 64 KB merge buffer
    __shared__ float mlds[2][2][32];

    const int tid  = threadIdx.x;
    const int bid  = blockIdx.x;
    const int n    = bid & 7;            // batch -> XCD locality
    const int q0   = (bid >> 3) * 64;
    const int w    = tid >> 6, lane = tid & 63;
    const int l31  = lane & 31;
    const int hi8  = (lane >> 5) << 3;
    const int qsub = w & 1, kvhalf = w >> 1;
    const int kvbase0 = kvhalf * 2048;

    const unsigned short* Kb = phiT + (size_t)n * HW_ * C_;
    const unsigned short* Vb = gC   + (size_t)n * C_ * HW_;

    // Q fragments: B-operand, col=q=lane&31, k = c = kk*16 + hi8 + e
    bf16x8 qf[16];
    {
        const unsigned short* qp = thetaT + ((size_t)n * HW_ + q0 + qsub * 32 + l31) * C_;
        #pragma unroll
        for (int kk = 0; kk < 16; ++kk)
            qf[kk] = *reinterpret_cast<const bf16x8*>(qp + kk * 16 + hi8);
    }

    f32x16 oacc[8];
    #pragma unroll
    for (int ncb = 0; ncb < 8; ++ncb)
        #pragma unroll
        for (int r = 0; r < 16; ++r) oacc[ncb][r] = 0.f;
    float m = -1e30f, l = 0.f;

    for (int t = 0; t < 64; ++t) {
        const int kv = kvbase0 + t * 32;
        const unsigned short* kt = Kb + ((size_t)(kv + l31)) * C_ + hi8;

        // S^T = K . Q^T : A-frags straight from global (16B each)
        f32x16 sA, sB;
        #pragma unroll
        for (int r = 0; r < 16; ++r) { sA[r] = 0.f; sB[r] = 0.f; }
        #pragma unroll
        for (int kk = 0; kk < 8; ++kk) {
            bf16x8 af = *reinterpret_cast<const bf16x8*>(kt + kk * 16);
            sA = MFMA32(af, qf[kk], sA);
        }
        #pragma unroll
        for (int kk = 8; kk < 16; ++kk) {
            bf16x8 af = *reinterpret_cast<const bf16x8*>(kt + kk * 16);
            sB = MFMA32(af, qf[kk], sB);
        }
        f32x16 s = sA + sB;   // lane holds 16 of this tile's 32 kv scores for q=l31

        // online softmax with defer-max (THR=8)
        float own = s[0];
        #pragma unroll
        for (int r = 1; r < 16; ++r) own = fmaxf(own, s[r]);
        float pmax = fmaxf(own, __shfl_xor(own, 32));
        if (__any(pmax > m + 8.f)) {
            float mn = fmaxf(m, pmax);
            float f  = __expf(m - mn);
            m = mn; l *= f;
            #pragma unroll
            for (int r = 0; r < 16; ++r) {
                int qr = (r & 3) + 8 * (r >> 2) + (hi8 >> 1);
                float fr = __shfl(f, qr);
                #pragma unroll
                for (int ncb = 0; ncb < 8; ++ncb) oacc[ncb][r] *= fr;
            }
        }
        float lsum = 0.f;
        #pragma unroll
        for (int r = 0; r < 16; ++r) {
            float e = __expf(s[r] - m);
            lsum += e;
            s[r] = e;
        }
        l += lsum;

        // P -> bf16 A-frags in-register, then PV with V-frags from global
        #pragma unroll
        for (int kk = 0; kk < 2; ++kk) {
            unsigned w0 = cvt_pk_bf16(s[kk * 8 + 0], s[kk * 8 + 1]);
            unsigned w1 = cvt_pk_bf16(s[kk * 8 + 2], s[kk * 8 + 3]);
            unsigned w2 = cvt_pk_bf16(s[kk * 8 + 4], s[kk * 8 + 5]);
            unsigned w3 = cvt_pk_bf16(s[kk * 8 + 6], s[kk * 8 + 7]);
            plswap(w0, w2);
            plswap(w1, w3);
            uint4 pw; pw.x = w0; pw.y = w1; pw.z = w2; pw.w = w3;
            bf16x8 pf = __builtin_bit_cast(bf16x8, pw);
            #pragma unroll
            for (int ncb = 0; ncb < 8; ++ncb) {
                bf16x8 vf = *reinterpret_cast<const bf16x8*>(
                    Vb + (size_t)(ncb * 32 + l31) * HW_ + kv + kk * 16 + hi8);
                oacc[ncb] = MFMA32(pf, vf, oacc[ncb]);
            }
        }
    }

    float l_tot = l + __shfl_xor(l, 32);

    // flash-merge the two kv-halves per q-subtile
    __syncthreads();
    if (kvhalf == 1) {
        #pragma unroll
        for (int r = 0; r < 16; ++r) {
            int qr = (r & 3) + 8 * (r >> 2) + (hi8 >> 1);
            #pragma unroll
            for (int ncb = 0; ncb < 8; ++ncb)
                Obuf[qsub][qr * 256 + ncb * 32 + l31] = oacc[ncb][r];
        }
        if (lane < 32) {
            mlds[qsub][0][l31] = m;
            mlds[qsub][1][l31] = l_tot;
        }
    }
    __syncthreads();
    if (kvhalf == 0) {
        float m2 = mlds[qsub][0][l31];
        float l2 = mlds[qsub][1][l31];
        float M  = fmaxf(m, m2);
        float f1 = __expf(m - M);
        float f2 = __expf(m2 - M);
        float Li = 1.0f / (l_tot * f1 + l2 * f2);
        unsigned short* op = tpgT + ((size_t)n * HW_ + q0 + qsub * 32) * C_;
        #pragma unroll
        for (int r = 0; r < 16; ++r) {
            int qr = (r & 3) + 8 * (r >> 2) + (hi8 >> 1);
            float f1r = __shfl(f1, qr);
            float f2r = __shfl(f2, qr);
            float Lir = __shfl(Li, qr);
            #pragma unroll
            for (int ncb = 0; ncb < 8; ++ncb) {
                float o2 = Obuf[qsub][qr * 256 + ncb * 32 + l31];
                float v  = (oacc[ncb][r] * f1r + o2 * f2r) * Lir;
                op[(size_t)qr * C_ + ncb * 32 + l31] = f2bf(v);
            }
        }
    }
}

// ---------------------------------------------------------------------------
// Kernel 3: p = w_out . tpg + b_out -> p:[N,C,HW] f32 + BN partial sums
// ---------------------------------------------------------------------------
__global__ __launch_bounds__(256) void outconv_kernel(
    const unsigned short* __restrict__ tpgT,
    const float* __restrict__ w_out, const float* __restrict__ b_out,
    float* __restrict__ p, float* __restrict__ bnsum, float* __restrict__ bnsumsq)
{
    __shared__ unsigned short Bl[64 * 264];
    const int tid = threadIdx.x;
    const int hw0 = blockIdx.x * 64;
    const int n   = blockIdx.y;
    const unsigned short* Tb = tpgT + (size_t)n * HW_ * C_;
    for (int i = 0; i < 8; ++i) {
        int e = tid + i * 256;
        int r = e >> 5, c8 = (e & 31) << 3;
        *reinterpret_cast<uint4*>(&Bl[r * 264 + c8]) =
            *reinterpret_cast<const uint4*>(Tb + ((size_t)hw0 + r) * C_ + c8);
    }
    __syncthreads();
    const int w = tid >> 6, lane = tid & 63, g16 = lane >> 4, l16 = lane & 15;

    for (int ot = 0; ot < 4; ++ot) {
        const int oB   = ot * 64;
        const int wrow = oB + w * 16 + l16;
        bf16x8 aw[8];
        #pragma unroll
        for (int kk = 0; kk < 8; ++kk) {
            const float* wp = w_out + (size_t)wrow * C_ + kk * 32 + g16 * 8;
            float4 f0 = *reinterpret_cast<const float4*>(wp);
            float4 f1 = *reinterpret_cast<const float4*>(wp + 4);
            aw[kk] = pack_bf8(f0, f1);
        }
        f32x4 acc[4];
        #pragma unroll
        for (int cb = 0; cb < 4; ++cb) { acc[cb][0]=0.f; acc[cb][1]=0.f; acc[cb][2]=0.f; acc[cb][3]=0.f; }
        #pragma unroll
        for (int kk = 0; kk < 8; ++kk) {
            #pragma unroll
            for (int cb = 0; cb < 4; ++cb) {
                bf16x8 b = *reinterpret_cast<const bf16x8*>(
                    &Bl[(cb * 16 + l16) * 264 + kk * 32 + g16 * 8]);
                acc[cb] = MFMA(aw[kk], b, acc[cb]);
            }
        }
        const int orow0 = oB + w * 16 + g16 * 4;
        float bj[4] = { b_out[orow0], b_out[orow0 + 1], b_out[orow0 + 2], b_out[orow0 + 3] };
        float s1[4] = {0.f,0.f,0.f,0.f}, s2[4] = {0.f,0.f,0.f,0.f};
        #pragma unroll
        for (int cb = 0; cb < 4; ++cb) {
            #pragma unroll
            for (int j = 0; j < 4; ++j) {
                float pv = acc[cb][j] + bj[j];
                p[((size_t)n * C_ + orow0 + j) * HW_ + hw0 + cb * 16 + l16] = pv;
                s1[j] += pv;
                s2[j] += pv * pv;
            }
        }
        #pragma unroll
        for (int j = 0; j < 4; ++j) {
            float a1 = s1[j], a2 = s2[j];
            a1 += __shfl_xor(a1, 1); a2 += __shfl_xor(a2, 1);
            a1 += __shfl_xor(a1, 2); a2 += __shfl_xor(a2, 2);
            a1 += __shfl_xor(a1, 4); a2 += __shfl_xor(a2, 4);
            a1 += __shfl_xor(a1, 8); a2 += __shfl_xor(a2, 8);
            if (l16 == 0) {
                atomicAdd(&bnsum[orow0 + j], a1);
                atomicAdd(&bnsumsq[orow0 + j], a2);
            }
        }
    }
}

// ---------------------------------------------------------------------------
// Kernel 4: finalize BN stats
// ---------------------------------------------------------------------------
__global__ void bnfin_kernel(const float* __restrict__ bnsum,
                             const float* __restrict__ bnsumsq,
                             const float* __restrict__ gamma,
                             const float* __restrict__ beta,
                             float* __restrict__ bnscale, float* __restrict__ bnshift)
{
    int c = threadIdx.x;
    const float cnt = (float)(N_ * HW_);
    float mean = bnsum[c] / cnt;
    float var  = bnsumsq[c] / cnt - mean * mean;
    float inv  = rsqrtf(var + 1e-5f);
    float sc   = gamma[c] * inv;
    bnscale[c] = sc;
    bnshift[c] = beta[c] - mean * sc;
}

// ---------------------------------------------------------------------------
// Kernel 5: z = (1-wg)*x + wg*(p*scale + shift)
// ---------------------------------------------------------------------------
__global__ __launch_bounds__(256) void final_kernel(
    const float* __restrict__ x, const float* __restrict__ p,
    const float* __restrict__ bnscale, const float* __restrict__ bnshift,
    const float* __restrict__ wgate, float* __restrict__ out)
{
    const float wg = *wgate;
    const float og = 1.0f - wg;
    const int total = N_ * C_ * HW_ / 4;
    for (int e = blockIdx.x * 256 + threadIdx.x; e < total; e += gridDim.x * 256) {
        int c = (e >> 10) & 255;
        float sc = bnscale[c], sh = bnshift[c];
        float4 xv = reinterpret_cast<const float4*>(x)[e];
        float4 pv = reinterpret_cast<const float4*>(p)[e];
        float4 z;
        z.x = og * xv.x + wg * (pv.x * sc + sh);
        z.y = og * xv.y + wg * (pv.y * sc + sh);
        z.z = og * xv.z + wg * (pv.z * sc + sh);
        z.w = og * xv.w + wg * (pv.w * sc + sh);
        reinterpret_cast<float4*>(out)[e] = z;
    }
}

extern "C" void kernel_launch(void* const* d_in, const int* in_sizes, int n_in,
                              void* d_out, int out_size, void* d_ws, size_t ws_size,
                              hipStream_t stream)
{
    (void)in_sizes; (void)n_in; (void)out_size; (void)ws_size;
    const float* x       = (const float*)d_in[0];
    const float* w_theta = (const float*)d_in[1];
    const float* b_theta = (const float*)d_in[2];
    const float* w_phi   = (const float*)d_in[3];
    const float* b_phi   = (const float*)d_in[4];
    const float* w_g     = (const float*)d_in[5];
    const float* b_g     = (const float*)d_in[6];
    const float* w_out   = (const float*)d_in[7];
    const float* b_out   = (const float*)d_in[8];
    const float* gamma   = (const float*)d_in[9];
    const float* beta    = (const float*)d_in[10];
    const float* wgate   = (const float*)d_in[11];
    float* out = (float*)d_out;

    char* ws = (char*)d_ws;
    unsigned short* thetaT = (unsigned short*)(ws + 0);           // 16 MiB
    unsigned short* phiT   = (unsigned short*)(ws + 16777216);    // 16 MiB
    unsigned short* gC     = (unsigned short*)(ws + 33554432);    // 16 MiB
    unsigned short* tpgT   = (unsigned short*)(ws + 50331648);    // 16 MiB
    float* p       = (float*)(ws + 0);            // 32 MiB, aliases dead theta/phi
    float* bnsum   = (float*)(ws + 67108864);
    float* bnsumsq = (float*)(ws + 67108864 + 1024);
    float* bnscale = (float*)(ws + 67108864 + 2048);
    float* bnshift = (float*)(ws + 67108864 + 3072);

    hipMemsetAsync(bnsum, 0, 2048, stream);

    qkv_kernel<<<dim3(64, 8), 256, 0, stream>>>(
        x, w_theta, b_theta, w_phi, b_phi, w_g, b_g, thetaT, phiT, gC);
    attn_kernel<<<dim3(512), 256, 0, stream>>>(thetaT, phiT, gC, tpgT);
    outconv_kernel<<<dim3(64, 8), 256, 0, stream>>>(tpgT, w_out, b_out, p, bnsum, bnsumsq);
    bnfin_kernel<<<1, 256, 0, stream>>>(bnsum, bnsumsq, gamma, beta, bnscale, bnshift);
    final_kernel<<<dim3(2048), 256, 0, stream>>>(x, p, bnscale, bnshift, wgate, out);
}

// Round 6
// 480.732 us; speedup vs baseline: 1.6296x; 1.6296x over previous
//
#include <hip/hip_runtime.h>

#define N_ 8
#define C_ 256
#define HW_ 4096
#define KVBLK 64

typedef __bf16 bf16x8 __attribute__((ext_vector_type(8)));
typedef float f32x4 __attribute__((ext_vector_type(4)));
typedef float f32x16 __attribute__((ext_vector_type(16)));
typedef unsigned short u16x8 __attribute__((ext_vector_type(8)));
typedef unsigned int uint2v __attribute__((ext_vector_type(2)));

#define MFMA(a, b, c)   __builtin_amdgcn_mfma_f32_16x16x32_bf16(a, b, c, 0, 0, 0)
#define MFMA32(a, b, c) __builtin_amdgcn_mfma_f32_32x32x16_bf16(a, b, c, 0, 0, 0)

static __device__ __forceinline__ unsigned short f2bf(float f) {
    union { float f; unsigned int u; } v; v.f = f;
    unsigned int u = v.u;
    return (unsigned short)((u + 0x7FFFu + ((u >> 16) & 1u)) >> 16);  // RNE
}

static __device__ __forceinline__ bf16x8 pack_bf8(float4 a, float4 b) {
    u16x8 t;
    t[0] = f2bf(a.x); t[1] = f2bf(a.y); t[2] = f2bf(a.z); t[3] = f2bf(a.w);
    t[4] = f2bf(b.x); t[5] = f2bf(b.y); t[6] = f2bf(b.z); t[7] = f2bf(b.w);
    return __builtin_bit_cast(bf16x8, t);
}

static __device__ __forceinline__ unsigned cvt_pk_bf16(float lo, float hi) {
    unsigned r;
    asm("v_cvt_pk_bf16_f32 %0, %1, %2" : "=v"(r) : "v"(lo), "v"(hi));
    return r;
}

static __device__ __forceinline__ void plswap(unsigned& a, unsigned& b) {
#if __has_builtin(__builtin_amdgcn_permlane32_swap)
    uint2v r = __builtin_amdgcn_permlane32_swap(a, b, false, false);
    a = r[0]; b = r[1];
#else
    asm volatile("v_permlane32_swap_b32 %0, %1" : "+v"(a), "+v"(b));
#endif
}

#define GLOAD_LDS16(src, dst)                                                   \
    __builtin_amdgcn_global_load_lds(                                           \
        (const __attribute__((address_space(1))) unsigned int*)(const void*)(src), \
        (__attribute__((address_space(3))) unsigned int*)(void*)(dst), 16, 0, 0)

// ---------------------------------------------------------------------------
// Kernel 1: theta/phi/g 1x1 convs (unchanged from r5, passing).
// ---------------------------------------------------------------------------
__global__ __launch_bounds__(256) void qkv_kernel(
    const float* __restrict__ x,
    const float* __restrict__ w_theta, const float* __restrict__ b_theta,
    const float* __restrict__ w_phi,   const float* __restrict__ b_phi,
    const float* __restrict__ w_g,     const float* __restrict__ b_g,
    unsigned short* __restrict__ thetaT, unsigned short* __restrict__ phiT,
    unsigned short* __restrict__ gC)
{
    __shared__ unsigned short xT[64 * 264];
    __shared__ unsigned short tile[64 * 72];
    const int tid = threadIdx.x;
    const int hw0 = blockIdx.x * 64;
    const int n   = blockIdx.y;
    const float* xb = x + (size_t)n * C_ * HW_;
    for (int i = 0; i < 16; ++i) {
        int e   = tid + i * 256;
        int c   = e >> 4;
        int hw4 = (e & 15) << 2;
        float4 v = *reinterpret_cast<const float4*>(xb + (size_t)c * HW_ + hw0 + hw4);
        xT[(hw4 + 0) * 264 + c] = f2bf(v.x);
        xT[(hw4 + 1) * 264 + c] = f2bf(v.y);
        xT[(hw4 + 2) * 264 + c] = f2bf(v.z);
        xT[(hw4 + 3) * 264 + c] = f2bf(v.w);
    }
    __syncthreads();

    const int w = tid >> 6, lane = tid & 63;
    const int g16 = lane >> 4, l16 = lane & 15;

    const float* Wp[3] = { w_theta, w_phi, w_g };
    const float* Bp[3] = { b_theta, b_phi, b_g };

    for (int ot = 0; ot < 4; ++ot) {
        const int oB    = ot * 64;
        const int wrow  = oB + w * 16 + l16;
        const int orow0 = oB + w * 16 + g16 * 4;
        #pragma unroll
        for (int wt = 0; wt < 3; ++wt) {
            const float* W = Wp[wt];
            bf16x8 aw[8];
            #pragma unroll
            for (int kk = 0; kk < 8; ++kk) {
                const float* wp = W + (size_t)wrow * C_ + kk * 32 + g16 * 8;
                float4 f0 = *reinterpret_cast<const float4*>(wp);
                float4 f1 = *reinterpret_cast<const float4*>(wp + 4);
                aw[kk] = pack_bf8(f0, f1);
            }
            f32x4 acc[4];
            #pragma unroll
            for (int cb = 0; cb < 4; ++cb) {
                acc[cb][0] = 0.f; acc[cb][1] = 0.f; acc[cb][2] = 0.f; acc[cb][3] = 0.f;
            }
            #pragma unroll
            for (int kk = 0; kk < 8; ++kk) {
                #pragma unroll
                for (int cb = 0; cb < 4; ++cb) {
                    bf16x8 b = *reinterpret_cast<const bf16x8*>(
                        &xT[(cb * 16 + l16) * 264 + kk * 32 + g16 * 8]);
                    acc[cb] = MFMA(aw[kk], b, acc[cb]);
                }
            }
            const float* bp = Bp[wt];
            float bj0 = bp[orow0], bj1 = bp[orow0 + 1], bj2 = bp[orow0 + 2], bj3 = bp[orow0 + 3];
            if (wt == 2) { bj0 = 0.f; bj1 = 0.f; bj2 = 0.f; bj3 = 0.f; }
            if (wt < 2) {
                const float sc = (wt == 0) ? 0.0625f : 1.0f;
                __syncthreads();
                #pragma unroll
                for (int cb = 0; cb < 4; ++cb) {
                    ushort4 pk;
                    pk.x = f2bf((acc[cb][0] + bj0) * sc);
                    pk.y = f2bf((acc[cb][1] + bj1) * sc);
                    pk.z = f2bf((acc[cb][2] + bj2) * sc);
                    pk.w = f2bf((acc[cb][3] + bj3) * sc);
                    *reinterpret_cast<ushort4*>(&tile[(cb * 16 + l16) * 72 + w * 16 + g16 * 4]) = pk;
                }
                __syncthreads();
                unsigned short* dst = (wt == 0) ? thetaT : phiT;
                #pragma unroll
                for (int i = 0; i < 2; ++i) {
                    int e = tid + i * 256;
                    int row = e >> 3, seg = (e & 7) << 3;
                    *reinterpret_cast<uint4*>(
                        &dst[((size_t)n * HW_ + hw0 + row) * C_ + oB + seg]) =
                        *reinterpret_cast<const uint4*>(&tile[row * 72 + seg]);
                }
            } else {
                #pragma unroll
                for (int cb = 0; cb < 4; ++cb) {
                    int hw = hw0 + cb * 16 + l16;
                    gC[((size_t)n * C_ + orow0 + 0) * HW_ + hw] = f2bf(acc[cb][0]);
                    gC[((size_t)n * C_ + orow0 + 1) * HW_ + hw] = f2bf(acc[cb][1]);
                    gC[((size_t)n * C_ + orow0 + 2) * HW_ + hw] = f2bf(acc[cb][2]);
                    gC[((size_t)n * C_ + orow0 + 3) * HW_ + hw] = f2bf(acc[cb][3]);
                }
            }
        }
    }
}

// ---------------------------------------------------------------------------
// Kernel 2: flash attention v3.  4 waves x 32 q-rows = 128 q / block, full kv
// sweep per wave (no merge).  KVBLK=64, double-buffered LDS (2x64KB) staged
// via global_load_lds w=16 with inverse-swizzled SOURCE (rule #21):
//   K tile [64][256]  read swz: elem ^= (row&31)<<3  (conflict-free)
//   V tile [256][64]  read swz: elem ^= (row&7)<<3   (<=4-way residual)
// Per step: STAGE(t+1) || COMPUTE(t) -> barrier.  Softmax/P-pack/defer-max
// byte-identical to the refcheck-verified r4 kernel.
// ---------------------------------------------------------------------------
__global__ __launch_bounds__(256, 1) void attn_kernel(
    const unsigned short* __restrict__ thetaT,
    const unsigned short* __restrict__ phiT,
    const unsigned short* __restrict__ gC,
    unsigned short* __restrict__ tpgT)
{
    __shared__ __align__(16) unsigned short Kbuf[2][64 * 256];   // 64 KB
    __shared__ __align__(16) unsigned short Vbuf[2][256 * 64];   // 64 KB

    const int tid  = threadIdx.x;
    const int bid  = blockIdx.x;
    const int n    = bid & 7;            // batch -> XCD locality
    const int qt   = bid >> 3;
    const int w    = tid >> 6, lane = tid & 63;
    const int l31  = lane & 31;
    const int hi   = lane >> 5;
    const int hi8  = hi << 3;

    const unsigned short* Kb = phiT + (size_t)n * HW_ * C_;
    const unsigned short* Vb = gC   + (size_t)n * C_ * HW_;

    // Q fragments: B-operand, col = q = lane&31, k-elems = kk*16 + hi8 + e
    bf16x8 qf[16];
    {
        const unsigned short* qp = thetaT + ((size_t)n * HW_ + qt * 128 + w * 32 + l31) * C_;
        #pragma unroll
        for (int kk = 0; kk < 16; ++kk)
            qf[kk] = *reinterpret_cast<const bf16x8*>(qp + kk * 16 + hi8);
    }

    f32x16 oacc[8];
    #pragma unroll
    for (int ncb = 0; ncb < 8; ++ncb)
        #pragma unroll
        for (int r = 0; r < 16; ++r) oacc[ncb][r] = 0.f;
    float m = -1e30f, l = 0.f;

    // ---- staging (per wave: 8 K-instrs covering rows w*16..+16, 8 V-instrs
    //      covering c-rows w*64..+64; source pre-swizzled, LDS linear) ----
    const int vrow_lane = lane >> 3;            // 0..7
    const int vslot_x   = ((lane & 7) ^ vrow_lane) << 3;

#define STAGE(buf, kv0)                                                          \
    do {                                                                         \
        _Pragma("unroll")                                                        \
        for (int i = 0; i < 8; ++i) {                                            \
            const int rl = w * 16 + i * 2 + hi;                                  \
            const unsigned short* src =                                          \
                Kb + (size_t)((kv0) + rl) * C_ + ((l31 ^ (rl & 31)) << 3);       \
            GLOAD_LDS16(src, &Kbuf[buf][(w * 16 + i * 2) * 256]);                \
        }                                                                        \
        _Pragma("unroll")                                                        \
        for (int i = 0; i < 8; ++i) {                                            \
            const int cr = w * 64 + i * 8 + vrow_lane;                           \
            const unsigned short* src = Vb + (size_t)cr * HW_ + (kv0) + vslot_x; \
            GLOAD_LDS16(src, &Vbuf[buf][(w * 64 + i * 8) * 64]);                 \
        }                                                                        \
    } while (0)

    STAGE(0, 0);
    __syncthreads();

    for (int t = 0; t < 64; ++t) {
        const int cur = t & 1;
        if (t < 63) STAGE(cur ^ 1, (t + 1) * KVBLK);

        // ---- S^T = K . Q^T  (two 32-kv subtiles, 2 acc chains each) ----
        f32x16 st[2];
        #pragma unroll
        for (int T = 0; T < 2; ++T) {
            f32x16 sA, sB;
            #pragma unroll
            for (int r = 0; r < 16; ++r) { sA[r] = 0.f; sB[r] = 0.f; }
            const unsigned short* Krow = &Kbuf[cur][(T * 32 + l31) * 256];
            const int swz = l31 << 3;
            #pragma unroll
            for (int kk = 0; kk < 8; ++kk) {
                bf16x8 af = *reinterpret_cast<const bf16x8*>(Krow + (((kk * 16) + hi8) ^ swz));
                sA = MFMA32(af, qf[kk], sA);
            }
            #pragma unroll
            for (int kk = 8; kk < 16; ++kk) {
                bf16x8 af = *reinterpret_cast<const bf16x8*>(Krow + (((kk * 16) + hi8) ^ swz));
                sB = MFMA32(af, qf[kk], sB);
            }
            st[T] = sA + sB;
        }

        // ---- online softmax with defer-max (THR=8), in-register ----
        float own = st[0][0];
        #pragma unroll
        for (int r = 1; r < 16; ++r) own = fmaxf(own, st[0][r]);
        #pragma unroll
        for (int r = 0; r < 16; ++r) own = fmaxf(own, st[1][r]);
        float pmax = fmaxf(own, __shfl_xor(own, 32));
        if (__any(pmax > m + 8.f)) {
            float mn = fmaxf(m, pmax);
            float f  = __expf(m - mn);
            m = mn; l *= f;
            #pragma unroll
            for (int r = 0; r < 16; ++r) {
                int qr = (r & 3) + 8 * (r >> 2) + (hi8 >> 1);
                float fr = __shfl(f, qr);
                #pragma unroll
                for (int ncb = 0; ncb < 8; ++ncb) oacc[ncb][r] *= fr;
            }
        }
        float lsum = 0.f;
        #pragma unroll
        for (int T = 0; T < 2; ++T)
            #pragma unroll
            for (int r = 0; r < 16; ++r) {
                float e = __expf(st[T][r] - m);
                lsum += e;
                st[T][r] = e;
            }
        l += lsum;

        // ---- P -> bf16 A-frags in-register, then PV ----
        #pragma unroll
        for (int T = 0; T < 2; ++T) {
            #pragma unroll
            for (int g = 0; g < 2; ++g) {
                unsigned w0 = cvt_pk_bf16(st[T][g * 8 + 0], st[T][g * 8 + 1]);
                unsigned w1 = cvt_pk_bf16(st[T][g * 8 + 2], st[T][g * 8 + 3]);
                unsigned w2 = cvt_pk_bf16(st[T][g * 8 + 4], st[T][g * 8 + 5]);
                unsigned w3 = cvt_pk_bf16(st[T][g * 8 + 6], st[T][g * 8 + 7]);
                plswap(w0, w2);
                plswap(w1, w3);
                uint4 pw; pw.x = w0; pw.y = w1; pw.z = w2; pw.w = w3;
                bf16x8 pf = __builtin_bit_cast(bf16x8, pw);
                const int kk2 = T * 2 + g;
                #pragma unroll
                for (int ncb = 0; ncb < 8; ++ncb) {
                    const int vr = ncb * 32 + l31;
                    bf16x8 vf = *reinterpret_cast<const bf16x8*>(
                        &Vbuf[cur][vr * 64 + (((kk2 * 16) + hi8) ^ ((vr & 7) << 3))]);
                    oacc[ncb] = MFMA32(pf, vf, oacc[ncb]);
                }
            }
        }
        __syncthreads();
    }
#undef STAGE

    // ---- normalize + write ----
    float l_tot = l + __shfl_xor(l, 32);
    float inv = 1.0f / l_tot;
    unsigned short* op = tpgT + ((size_t)n * HW_ + qt * 128 + w * 32) * C_;
    #pragma unroll
    for (int r = 0; r < 16; ++r) {
        int qr = (r & 3) + 8 * (r >> 2) + (hi8 >> 1);
        float Lir = __shfl(inv, qr);
        #pragma unroll
        for (int ncb = 0; ncb < 8; ++ncb)
            op[(size_t)qr * C_ + ncb * 32 + l31] = f2bf(oacc[ncb][r] * Lir);
    }
}

// ---------------------------------------------------------------------------
// Kernel 3: p = w_out . tpg + b_out -> p:[N,C,HW] f32 + BN partial sums
// ---------------------------------------------------------------------------
__global__ __launch_bounds__(256) void outconv_kernel(
    const unsigned short* __restrict__ tpgT,
    const float* __restrict__ w_out, const float* __restrict__ b_out,
    float* __restrict__ p, float* __restrict__ bnsum, float* __restrict__ bnsumsq)
{
    __shared__ unsigned short Bl[64 * 264];
    const int tid = threadIdx.x;
    const int hw0 = blockIdx.x * 64;
    const int n   = blockIdx.y;
    const unsigned short* Tb = tpgT + (size_t)n * HW_ * C_;
    for (int i = 0; i < 8; ++i) {
        int e = tid + i * 256;
        int r = e >> 5, c8 = (e & 31) << 3;
        *reinterpret_cast<uint4*>(&Bl[r * 264 + c8]) =
            *reinterpret_cast<const uint4*>(Tb + ((size_t)hw0 + r) * C_ + c8);
    }
    __syncthreads();
    const int w = tid >> 6, lane = tid & 63, g16 = lane >> 4, l16 = lane & 15;

    for (int ot = 0; ot < 4; ++ot) {
        const int oB   = ot * 64;
        const int wrow = oB + w * 16 + l16;
        bf16x8 aw[8];
        #pragma unroll
        for (int kk = 0; kk < 8; ++kk) {
            const float* wp = w_out + (size_t)wrow * C_ + kk * 32 + g16 * 8;
            float4 f0 = *reinterpret_cast<const float4*>(wp);
            float4 f1 = *reinterpret_cast<const float4*>(wp + 4);
            aw[kk] = pack_bf8(f0, f1);
        }
        f32x4 acc[4];
        #pragma unroll
        for (int cb = 0; cb < 4; ++cb) { acc[cb][0]=0.f; acc[cb][1]=0.f; acc[cb][2]=0.f; acc[cb][3]=0.f; }
        #pragma unroll
        for (int kk = 0; kk < 8; ++kk) {
            #pragma unroll
            for (int cb = 0; cb < 4; ++cb) {
                bf16x8 b = *reinterpret_cast<const bf16x8*>(
                    &Bl[(cb * 16 + l16) * 264 + kk * 32 + g16 * 8]);
                acc[cb] = MFMA(aw[kk], b, acc[cb]);
            }
        }
        const int orow0 = oB + w * 16 + g16 * 4;
        float bj[4] = { b_out[orow0], b_out[orow0 + 1], b_out[orow0 + 2], b_out[orow0 + 3] };
        float s1[4] = {0.f,0.f,0.f,0.f}, s2[4] = {0.f,0.f,0.f,0.f};
        #pragma unroll
        for (int cb = 0; cb < 4; ++cb) {
            #pragma unroll
            for (int j = 0; j < 4; ++j) {
                float pv = acc[cb][j] + bj[j];
                p[((size_t)n * C_ + orow0 + j) * HW_ + hw0 + cb * 16 + l16] = pv;
                s1[j] += pv;
                s2[j] += pv * pv;
            }
        }
        #pragma unroll
        for (int j = 0; j < 4; ++j) {
            float a1 = s1[j], a2 = s2[j];
            a1 += __shfl_xor(a1, 1); a2 += __shfl_xor(a2, 1);
            a1 += __shfl_xor(a1, 2); a2 += __shfl_xor(a2, 2);
            a1 += __shfl_xor(a1, 4); a2 += __shfl_xor(a2, 4);
            a1 += __shfl_xor(a1, 8); a2 += __shfl_xor(a2, 8);
            if (l16 == 0) {
                atomicAdd(&bnsum[orow0 + j], a1);
                atomicAdd(&bnsumsq[orow0 + j], a2);
            }
        }
    }
}

// ---------------------------------------------------------------------------
// Kernel 4: finalize BN stats
// ---------------------------------------------------------------------------
__global__ void bnfin_kernel(const float* __restrict__ bnsum,
                             const float* __restrict__ bnsumsq,
                             const float* __restrict__ gamma,
                             const float* __restrict__ beta,
                             float* __restrict__ bnscale, float* __restrict__ bnshift)
{
    int c = threadIdx.x;
    const float cnt = (float)(N_ * HW_);
    float mean = bnsum[c] / cnt;
    float var  = bnsumsq[c] / cnt - mean * mean;
    float inv  = rsqrtf(var + 1e-5f);
    float sc   = gamma[c] * inv;
    bnscale[c] = sc;
    bnshift[c] = beta[c] - mean * sc;
}

// ---------------------------------------------------------------------------
// Kernel 5: z = (1-wg)*x + wg*(p*scale + shift)
// ---------------------------------------------------------------------------
__global__ __launch_bounds__(256) void final_kernel(
    const float* __restrict__ x, const float* __restrict__ p,
    const float* __restrict__ bnscale, const float* __restrict__ bnshift,
    const float* __restrict__ wgate, float* __restrict__ out)
{
    const float wg = *wgate;
    const float og = 1.0f - wg;
    const int total = N_ * C_ * HW_ / 4;
    for (int e = blockIdx.x * 256 + threadIdx.x; e < total; e += gridDim.x * 256) {
        int c = (e >> 10) & 255;
        float sc = bnscale[c], sh = bnshift[c];
        float4 xv = reinterpret_cast<const float4*>(x)[e];
        float4 pv = reinterpret_cast<const float4*>(p)[e];
        float4 z;
        z.x = og * xv.x + wg * (pv.x * sc + sh);
        z.y = og * xv.y + wg * (pv.y * sc + sh);
        z.z = og * xv.z + wg * (pv.z * sc + sh);
        z.w = og * xv.w + wg * (pv.w * sc + sh);
        reinterpret_cast<float4*>(out)[e] = z;
    }
}

extern "C" void kernel_launch(void* const* d_in, const int* in_sizes, int n_in,
                              void* d_out, int out_size, void* d_ws, size_t ws_size,
                              hipStream_t stream)
{
    (void)in_sizes; (void)n_in; (void)out_size; (void)ws_size;
    const float* x       = (const float*)d_in[0];
    const float* w_theta = (const float*)d_in[1];
    const float* b_theta = (const float*)d_in[2];
    const float* w_phi   = (const float*)d_in[3];
    const float* b_phi   = (const float*)d_in[4];
    const float* w_g     = (const float*)d_in[5];
    const float* b_g     = (const float*)d_in[6];
    const float* w_out   = (const float*)d_in[7];
    const float* b_out   = (const float*)d_in[8];
    const float* gamma   = (const float*)d_in[9];
    const float* beta    = (const float*)d_in[10];
    const float* wgate   = (const float*)d_in[11];
    float* out = (float*)d_out;

    char* ws = (char*)d_ws;
    unsigned short* thetaT = (unsigned short*)(ws + 0);           // 16 MiB
    unsigned short* phiT   = (unsigned short*)(ws + 16777216);    // 16 MiB
    unsigned short* gC     = (unsigned short*)(ws + 33554432);    // 16 MiB
    unsigned short* tpgT   = (unsigned short*)(ws + 50331648);    // 16 MiB
    float* p       = (float*)(ws + 0);            // 32 MiB, aliases dead theta/phi
    float* bnsum   = (float*)(ws + 67108864);
    float* bnsumsq = (float*)(ws + 67108864 + 1024);
    float* bnscale = (float*)(ws + 67108864 + 2048);
    float* bnshift = (float*)(ws + 67108864 + 3072);

    hipMemsetAsync(bnsum, 0, 2048, stream);

    qkv_kernel<<<dim3(64, 8), 256, 0, stream>>>(
        x, w_theta, b_theta, w_phi, b_phi, w_g, b_g, thetaT, phiT, gC);
    attn_kernel<<<dim3(256), 256, 0, stream>>>(thetaT, phiT, gC, tpgT);
    outconv_kernel<<<dim3(64, 8), 256, 0, stream>>>(tpgT, w_out, b_out, p, bnsum, bnsumsq);
    bnfin_kernel<<<1, 256, 0, stream>>>(bnsum, bnsumsq, gamma, beta, bnscale, bnshift);
    final_kernel<<<dim3(2048), 256, 0, stream>>>(x, p, bnscale, bnshift, wgate, out);
}